// Round 10
// baseline (272.922 us; speedup 1.0000x reference)
//
#include <hip/hip_runtime.h>
#include <hip/hip_bf16.h>

// Problem constants
#define BATCH 32
#define NNODE 4096
#define CIN 32
#define COUT 64
#define KDEG 5
#define POOL 4
#define NNZ_E 65536
#define BC (BATCH * CIN)         // 1024 bf16 cols per node-row
#define TBF ((size_t)NNODE * BC) // elems per Chebyshev level (bf16 storage)
// Plane layout: t[k][slice][node][8 bf16], slice = col/8, 128 slices.
// One slice plane = 4096 * 16 B = 64 KB (fits one block's LDS exactly).

typedef short s16x8 __attribute__((ext_vector_type(8)));
typedef float f32x4 __attribute__((ext_vector_type(4)));
typedef int   i32x4 __attribute__((ext_vector_type(4)));
typedef unsigned long long u64;

// float -> bf16 bits, round-to-nearest-even
__device__ __forceinline__ unsigned short f2bf(float f) {
    union { float f; unsigned int u; } v; v.f = f;
    unsigned int u = v.u;
    u += 0x7fffu + ((u >> 16) & 1u);
    return (unsigned short)(u >> 16);
}
__device__ __forceinline__ unsigned int pack2(float a, float b) {
    return (unsigned int)f2bf(a) | ((unsigned int)f2bf(b) << 16);
}
__device__ __forceinline__ u64 pack4(float a, float b, float c, float d) {
    return (u64)pack2(a, b) | ((u64)pack2(c, d) << 32);
}
// bf16 pair unpack from packed int: low half / high half as fp32
__device__ __forceinline__ float blo(int x) { return __int_as_float(x << 16); }
__device__ __forceinline__ float bhi(int x) { return __int_as_float(x & 0xffff0000); }

// ---------------- prep: transpose x -> t0 planes (bf16), edge hist, pack W ------

__global__ void prep_kernel(const float* __restrict__ x, unsigned short* __restrict__ t0,
                            const int* __restrict__ erow, int* __restrict__ cnt,
                            const float* __restrict__ W, unsigned short* __restrict__ WB) {
    int idx = blockIdx.x * 256 + threadIdx.x;   // [0, 1048576)
    int n   = idx >> 8;
    int rem = idx & 255;
    int b   = rem >> 3;
    int c4  = rem & 7;                          // which float4 of the 8 channels
    float4 v = ((const float4*)x)[(b * NNODE + n) * 8 + c4];
    // cols b*32+c4*4 .. +4 -> slice = b*4 + (c4>>1), half (c4&1) of the 8-col entry
    int slice = b * 4 + (c4 >> 1);
    size_t ui = ((size_t)slice * NNODE + n) * 2 + (c4 & 1);
    ((u64*)t0)[ui] = pack4(v.x, v.y, v.z, v.w);

    if (idx < NNZ_E) atomicAdd(&cnt[erow[idx]], 1);

    if (idx < KDEG * COUT * CIN) {
        int c = idx & 31;
        int rest = idx >> 5;
        int o = rest & 63;
        int k = rest >> 6;
        // WB[k][o][c] : B-fragment order for mfma_16x16x32 (lane nn=o, kk=c)
        WB[idx] = f2bf(W[(c * KDEG + k) * COUT + o]);
    }
}

// ---------------- scan: cnt -> row_start / cursor ----------------

__global__ void scan_kernel(const int* __restrict__ cnt, int* __restrict__ row_start,
                            int* __restrict__ cursor) {
    __shared__ int sums[256];
    int tid = threadIdx.x;
    int local[16];
    int s = 0;
#pragma unroll
    for (int i = 0; i < 16; i++) { local[i] = cnt[tid * 16 + i]; s += local[i]; }
    sums[tid] = s;
    __syncthreads();
    for (int off = 1; off < 256; off <<= 1) {
        int v = 0;
        if (tid >= off) v = sums[tid - off];
        __syncthreads();
        if (tid >= off) sums[tid] += v;
        __syncthreads();
    }
    int base = sums[tid] - s;
    int run = base;
#pragma unroll
    for (int i = 0; i < 16; i++) {
        int r = tid * 16 + i;
        row_start[r] = run;
        cursor[r] = run;
        run += local[i];
    }
    if (tid == 255) row_start[NNODE] = sums[255];
}

// ---------------- scatter edges row-sorted as (col, val_bits) pairs ----------------

__global__ void scatter_kernel(const int* __restrict__ erow, const int* __restrict__ ecol,
                               const float* __restrict__ eval, int* __restrict__ cursor,
                               int2* __restrict__ es) {
    int e = blockIdx.x * blockDim.x + threadIdx.x;
    if (e < NNZ_E) {
        int pos = atomicAdd(&cursor[erow[e]], 1);
        es[pos] = make_int2(ecol[e], __float_as_int(eval[e]));
    }
}

// ---------------- LDS-gather SpMM: out = scale*(L@in) - sub ----------------
// Block = (slice, quarter). Stages its slice plane (64 KB) in LDS, then each
// thread computes 4 full rows x 8 cols with ds_read_b128 gathers. No cross-lane
// reduction. Grid 512 = 128 slices x 4 row-quarters.

__global__ __launch_bounds__(256) void spmm_lds_kernel(
        const unsigned short* __restrict__ in, const unsigned short* __restrict__ sub,
        unsigned short* __restrict__ out, float scale, int has_sub,
        const int* __restrict__ row_start, const int2* __restrict__ es) {
    __shared__ i32x4 lds[NNODE];   // 64 KB: lds[node] = this slice's 8 bf16 cols
    int bx      = blockIdx.x;      // [0, 512)
    int slice   = bx >> 2;
    int quarter = bx & 3;
    int tid     = threadIdx.x;

    // stage the whole slice plane (coalesced 64 KB stream)
    const i32x4* gin = (const i32x4*)in + (size_t)slice * NNODE;
    for (int i = tid; i < NNODE; i += 256) lds[i] = gin[i];
    __syncthreads();

    const i32x4* sub4 = (const i32x4*)sub + (size_t)slice * NNODE;
    i32x4*       out4 = (i32x4*)out + (size_t)slice * NNODE;
    int rbase = quarter * 1024 + tid * 4;

#pragma unroll
    for (int rr = 0; rr < 4; rr++) {
        int r = rbase + rr;
        int beg = row_start[r], end = row_start[r + 1];
        i32x4 sv = {0, 0, 0, 0};
        if (has_sub) sv = __builtin_nontemporal_load(sub4 + r);

        float4 accl = {0.f, 0.f, 0.f, 0.f};
        float4 acch = {0.f, 0.f, 0.f, 0.f};

        for (int p = beg; p < end; p += 8) {
            float v[8];
            i32x4 g[8];
#pragma unroll
            for (int j = 0; j < 8; j++) {
                int idx = p + j;
                int src = idx < end ? idx : beg;   // beg valid: loop entered
                int2 e = es[src];
                v[j] = idx < end ? __int_as_float(e.y) : 0.f;
                g[j] = lds[e.x];                    // ds_read_b128
            }
#pragma unroll
            for (int j = 0; j < 8; j++) {
                accl.x += v[j] * blo(g[j][0]); accl.y += v[j] * bhi(g[j][0]);
                accl.z += v[j] * blo(g[j][1]); accl.w += v[j] * bhi(g[j][1]);
                acch.x += v[j] * blo(g[j][2]); acch.y += v[j] * bhi(g[j][2]);
                acch.z += v[j] * blo(g[j][3]); acch.w += v[j] * bhi(g[j][3]);
            }
        }

        float o0, o1, o2, o3, o4, o5, o6, o7;
        if (has_sub) {
            o0 = scale * accl.x - blo(sv[0]); o1 = scale * accl.y - bhi(sv[0]);
            o2 = scale * accl.z - blo(sv[1]); o3 = scale * accl.w - bhi(sv[1]);
            o4 = scale * acch.x - blo(sv[2]); o5 = scale * acch.y - bhi(sv[2]);
            o6 = scale * acch.z - blo(sv[3]); o7 = scale * acch.w - bhi(sv[3]);
        } else {
            o0 = accl.x; o1 = accl.y; o2 = accl.z; o3 = accl.w;
            o4 = acch.x; o5 = acch.y; o6 = acch.z; o7 = acch.w;
        }
        i32x4 ov;
        ov[0] = (int)pack2(o0, o1);
        ov[1] = (int)pack2(o2, o3);
        ov[2] = (int)pack2(o4, o5);
        ov[3] = (int)pack2(o6, o7);
        out4[r] = ov;
    }
}

// ---------------- MFMA GEMM + bias + ReLU + maxpool ----------------
// One wave = one (batch b, 16-node tile). D row = quad*4+r -> lane's 4 acc rows
// are exactly one pool group; ReLU+maxpool collapse to in-lane max. No LDS.
// A-frag (channels q*8..+8 of batch b) = plane entry (slice=b*4+q, node), 16 B.

__global__ __launch_bounds__(256) void gemm_mfma_pool_kernel(
        const unsigned short* __restrict__ tbase, const unsigned short* __restrict__ WB,
        const float* __restrict__ bias, float* __restrict__ out) {
    int gtid = blockIdx.x * 256 + threadIdx.x;
    int lane = threadIdx.x & 63;
    int wid  = gtid >> 6;            // [0, 8192)
    int b    = wid >> 8;             // [0, 32)
    int n0   = (wid & 255) << 4;     // node tile base
    int m    = lane & 15;
    int q    = lane >> 4;

    f32x4 acc[4] = {{0.f,0.f,0.f,0.f},{0.f,0.f,0.f,0.f},
                    {0.f,0.f,0.f,0.f},{0.f,0.f,0.f,0.f}};

    const unsigned short* abase =
        tbase + (((size_t)(b * 4 + q) * NNODE) + n0 + m) * 8;
    const unsigned short* wbase = WB + m * 32 + q * 8;

#pragma unroll
    for (int k = 0; k < KDEG; k++) {
        s16x8 a = *(const s16x8*)(abase + (size_t)k * TBF);
#pragma unroll
        for (int ot = 0; ot < 4; ot++) {
            s16x8 bf = *(const s16x8*)(wbase + ((k * 64) + ot * 16) * 32);
            acc[ot] = __builtin_amdgcn_mfma_f32_16x16x32_bf16(a, bf, acc[ot], 0, 0, 0);
        }
    }

    size_t orow = ((size_t)b * (NNODE / POOL) + (n0 >> 2) + q) * COUT;
#pragma unroll
    for (int ot = 0; ot < 4; ot++) {
        float bi = bias[ot * 16 + m];
        float r0 = acc[ot][0] + bi; r0 = r0 > 0.f ? r0 : 0.f;
        float r1 = acc[ot][1] + bi; r1 = r1 > 0.f ? r1 : 0.f;
        float r2 = acc[ot][2] + bi; r2 = r2 > 0.f ? r2 : 0.f;
        float r3 = acc[ot][3] + bi; r3 = r3 > 0.f ? r3 : 0.f;
        float mx = r0 > r1 ? r0 : r1;
        mx = mx > r2 ? mx : r2;
        mx = mx > r3 ? mx : r3;
        out[orow + ot * 16 + m] = mx;
    }
}

// ---------------- launch ----------------

extern "C" void kernel_launch(void* const* d_in, const int* in_sizes, int n_in,
                              void* d_out, int out_size, void* d_ws, size_t ws_size,
                              hipStream_t stream) {
    const float* x    = (const float*)d_in[0];
    const float* eval = (const float*)d_in[1];
    const float* W    = (const float*)d_in[2];
    const float* bias = (const float*)d_in[3];
    const int*   erow = (const int*)d_in[4];
    const int*   ecol = (const int*)d_in[5];
    float* out = (float*)d_out;

    char* base = (char*)d_ws;
    unsigned short* tb = (unsigned short*)base;     // 5 levels x 8 MB (bf16 planes)
    unsigned short* t0 = tb;
    unsigned short* t1 = tb + 1 * TBF;
    unsigned short* t2 = tb + 2 * TBF;
    unsigned short* t3 = tb + 3 * TBF;
    unsigned short* t4 = tb + 4 * TBF;

    size_t off = 5 * TBF * sizeof(unsigned short);
    int2* es       = (int2*)(base + off);  off += (size_t)NNZ_E * sizeof(int2);
    int* cnt       = (int*)(base + off);   off += (size_t)NNODE * sizeof(int);
    int* row_start = (int*)(base + off);   off += (size_t)(NNODE + 1) * sizeof(int);
    int* cursor    = (int*)(base + off);   off += (size_t)NNODE * sizeof(int);
    off = (off + 63) & ~(size_t)63;
    unsigned short* WB = (unsigned short*)(base + off);

    // parallel CSR build + transpose + W pack (d_ws re-poisoned -> rebuild each call)
    (void)hipMemsetAsync(cnt, 0, NNODE * sizeof(int), stream);
    prep_kernel<<<TBF / 4 / 256, 256, 0, stream>>>(x, t0, erow, cnt, W, WB);
    scan_kernel<<<1, 256, 0, stream>>>(cnt, row_start, cursor);
    scatter_kernel<<<NNZ_E / 256, 256, 0, stream>>>(erow, ecol, eval, cursor, es);

    // Chebyshev recursion: LDS-gather, plane-sliced, bf16 / fp32 accumulate
    spmm_lds_kernel<<<512, 256, 0, stream>>>(t0, nullptr, t1, 1.0f, 0, row_start, es);
    spmm_lds_kernel<<<512, 256, 0, stream>>>(t1, t0, t2, 2.0f, 1, row_start, es);
    spmm_lds_kernel<<<512, 256, 0, stream>>>(t2, t1, t3, 2.0f, 1, row_start, es);
    spmm_lds_kernel<<<512, 256, 0, stream>>>(t3, t2, t4, 2.0f, 1, row_start, es);

    // MFMA GEMM + bias + relu + maxpool (bf16 inputs, fp32 accumulate)
    gemm_mfma_pool_kernel<<<(BATCH * (NNODE / 16) * 64) / 256, 256, 0, stream>>>(
        tb, WB, bias, out);
}